// Round 3
// baseline (661.119 us; speedup 1.0000x reference)
//
#include <hip/hip_runtime.h>

// TinyNeRF fused MLP, fp16 MFMA 16x16x32, fp32 accum.
// Round-3: ALL weights persistent in LDS (exactly 160 KB), one 1024-thread
// block per CU (16 waves = 4/SIMD), ZERO barriers after the one-time stage.
// Each wave independently processes 4 chunks of 64 points.
//
// LDS image (halves), built by prep into d_ws then staged once per block:
//   G1A/G1B: g1 [2][64 rows][40 halves] stride 80B, cols 36..39 zero, NO swz.
//            (A-frag over-reads past row end hit garbage that multiplies
//             B-frag zeros at k>=36 -- harmless by construction.)
//   G2A..FBC: six [64][128] chunks (g2,g3,g4,f halves), stride 256B,
//            XOR-swizzle ((o&7)<<4), K-axis permk'd.
//   C1C: c1 [64][160] stride 320B, swz ((o&3)<<4); cols 0..127 permk'd
//        feature, 128..151 identity dir, 152..159 = d_w stash (rows 0..15,
//        d_perm[8*o+j]) -- these cells only ever multiply B zeros.
//   C2C: c2 [16][64] stride 128B, swz ((o&7)<<4), rows 0..2 real.
// Total = 81920 halves = 163840 B exactly.

typedef _Float16 half8 __attribute__((ext_vector_type(8)));
typedef _Float16 half2v __attribute__((ext_vector_type(2)));
typedef float f32x4 __attribute__((ext_vector_type(4)));

typedef __attribute__((address_space(1))) const unsigned int GU32;
typedef __attribute__((address_space(3))) unsigned int LU32;

#define MFMA16(A,B,C) __builtin_amdgcn_mfma_f32_16x16x32_f16(A,B,C,0,0,0)

#define G1A 0
#define G1B 2560
#define G2A 5120
#define G2B 13312
#define G3A 21504
#define G3B 29696
#define G4A 37888
#define G4B 46080
#define FAC 54272
#define FBC 62464
#define C1C 70656
#define C2C 80896
#define IMG_HALVES 81920

// K-axis permutation: B-slot (ks,g,jj) holds output dim
// (2ks + jj>>2)*16 + g*4 + (jj&3) of the previous layer.
__device__ __forceinline__ int permk(int s){
  int ks = s >> 5, gg = (s >> 3) & 3, jj = s & 7;
  return (2*ks + (jj >> 2))*16 + gg*4 + (jj & 3);
}

__global__ void prep(const float* __restrict__ g1w, const float* __restrict__ g2w,
                     const float* __restrict__ g3w, const float* __restrict__ g4w,
                     const float* __restrict__ dw,  const float* __restrict__ fw,
                     const float* __restrict__ c1w, const float* __restrict__ c2w,
                     _Float16* __restrict__ img) {
  int i = blockIdx.x*256 + threadIdx.x;
  if (i >= IMG_HALVES) return;
  float v = 0.f;
  size_t byteoff;
  if (i < G2A) {                       // g1: linear [2][64][40]
    int hf = (i < G1B) ? 0 : 1;
    int r = i - hf*G1B;
    int o = r / 40, s = r % 40;
    v = (s < 36) ? g1w[s*128 + hf*64 + o] : 0.f;
    byteoff = (size_t)i*2;
  } else if (i < C1C) {                // six [64][128] chunks, swz7, permk
    int ci = (i - G2A) >> 13;
    int r  = (i - G2A) & 8191;
    int o = r >> 7, s = r & 127;
    const float* W = (ci < 2) ? g2w : (ci < 4) ? g3w : (ci < 6) ? g4w : fw;
    int obase = (ci & 1)*64;
    v = W[permk(s)*128 + obase + o];
    byteoff = (size_t)(G2A + ci*8192)*2 + o*256 + ((2*s) ^ ((o & 7) << 4));
  } else if (i < C2C) {                // c1 [64][160], swz2
    int r = i - C1C;
    int o = r / 160, s = r % 160;
    if (s < 128)      v = c1w[permk(s)*64 + o];
    else if (s < 152) v = c1w[s*64 + o];
    else if (o < 16)  v = dw[permk(8*o + (s - 152))];   // d_w stash
    else              v = 0.f;
    byteoff = (size_t)C1C*2 + o*320 + ((2*s) ^ ((o & 3) << 4));
  } else {                             // c2 [16][64], swz7
    int r = i - C2C;
    int o = r >> 6, s = r & 63;
    v = (o < 3) ? c2w[permk(s)*3 + o] : 0.f;
    byteoff = (size_t)C2C*2 + o*128 + ((2*s) ^ ((o & 7) << 4));
  }
  *(_Float16*)((char*)img + byteoff) = (_Float16)v;
}

__device__ __forceinline__ half8 mk8(uint2 a, uint2 b){
  union { unsigned int u[4]; half8 h; } x;
  x.u[0]=a.x; x.u[1]=a.y; x.u[2]=b.x; x.u[3]=b.y; return x.h;
}
__device__ __forceinline__ half8 mkh8(float a,float b,float c,float d,
                                      float e,float f,float g,float h){
  half8 r; r[0]=(_Float16)a; r[1]=(_Float16)b; r[2]=(_Float16)c; r[3]=(_Float16)d;
  r[4]=(_Float16)e; r[5]=(_Float16)f; r[6]=(_Float16)g; r[7]=(_Float16)h; return r;
}
__device__ __forceinline__ uint2 pack4(float a0,float a1,float a2,float a3,bool relu){
  if (relu){ a0=fmaxf(a0,0.f); a1=fmaxf(a1,0.f); a2=fmaxf(a2,0.f); a3=fmaxf(a3,0.f); }
  union { _Float16 h[4]; uint2 u; } x;
  x.h[0]=(_Float16)a0; x.h[1]=(_Float16)a1; x.h[2]=(_Float16)a2; x.h[3]=(_Float16)a3;
  return x.u;
}

// one og-half: O=64 (og 0..3) from persistent-LDS chunk at `buf`
template<int KROWB, int KS, int PKB, bool RELU, int SWZM>
__device__ __forceinline__ void chunk64(const _Float16* buf, int lane,
                                        const float* __restrict__ bias,
                                        const half8 (&bf)[4][5], uint2 (&pk)[8][4]) {
  const int g = lane >> 4, n = lane & 15;
  const int swz = (n & SWZM) << 4;
  const char* lb = (const char*)buf + n*KROWB;
#pragma unroll
  for (int og = 0; og < 4; ++og) {
    half8 wf[KS];
#pragma unroll
    for (int ks = 0; ks < KS; ++ks)
      wf[ks] = *(const half8*)(lb + og*16*KROWB + ((ks*64 + g*16) ^ swz));
    f32x4 bv = *(const f32x4*)(bias + og*16 + g*4);
    f32x4 acc[4];
#pragma unroll
    for (int st = 0; st < 4; ++st) acc[st] = bv;
    __builtin_amdgcn_s_setprio(1);
#pragma unroll
    for (int ks = 0; ks < KS; ++ks)
#pragma unroll
      for (int st = 0; st < 4; ++st)
        acc[st] = MFMA16(wf[ks], bf[st][ks], acc[st]);
    __builtin_amdgcn_s_setprio(0);
#pragma unroll
    for (int st = 0; st < 4; ++st)
      pk[PKB+og][st] = pack4(acc[st][0], acc[st][1], acc[st][2], acc[st][3], RELU);
  }
}

#define REB4() do{ \
  _Pragma("unroll") \
  for (int st_ = 0; st_ < 4; ++st_){ \
    half8 n0 = mk8(pk[0][st_], pk[1][st_]); \
    half8 n1 = mk8(pk[2][st_], pk[3][st_]); \
    half8 n2 = mk8(pk[4][st_], pk[5][st_]); \
    half8 n3 = mk8(pk[6][st_], pk[7][st_]); \
    bf[st_][0]=n0; bf[st_][1]=n1; bf[st_][2]=n2; bf[st_][3]=n3; \
  } \
}while(0)

__global__ __launch_bounds__(1024, 4) void nerf_fused(
    const float* __restrict__ pos, const float* __restrict__ dirs,
    const _Float16* __restrict__ img,
    const float* __restrict__ b1, const float* __restrict__ b2,
    const float* __restrict__ b3, const float* __restrict__ b4,
    const float* __restrict__ bd, const float* __restrict__ bfl,
    const float* __restrict__ bc1, const float* __restrict__ bc2,
    float* __restrict__ out, int N) {
  __shared__ __align__(16) _Float16 W[IMG_HALVES];   // 160 KB exactly
  const int tid = threadIdx.x, wave = tid >> 6, lane = tid & 63;
  const int g = lane >> 4, n = lane & 15;

  // one-time weight stage: 1024 thr x 10 x 16B = 163840 B
#pragma unroll
  for (int r = 0; r < 10; ++r)
    __builtin_amdgcn_global_load_lds((GU32*)((const char*)img + tid*16 + (size_t)r*16384),
                                     (LU32*)((char*)&W[0] + tid*16 + r*16384), 16, 0, 0);
  __syncthreads();   // the only barrier

  half8 bf[4][5];
  uint2 pk[8][4];
  half8 dirf[4];
  const float PI = 3.14159265358979f;
  half8 z = {};

  for (int it = 0; it < 4; ++it) {
    const int pbase = (blockIdx.x*64 + wave*4 + it)*64;

    // ---- encode directly into B-fragment form ----
#pragma unroll
    for (int st = 0; st < 4; ++st) {
      int p = pbase + st*16 + n;
      float S[3][6], C[3][6];
      const float* pp = pos + (size_t)p*3;
#pragma unroll
      for (int d = 0; d < 3; ++d) {
        float x = pp[d]*PI;
        float s = __sinf(x), c = __cosf(x);
        S[d][0]=s; C[d][0]=c;
#pragma unroll
        for (int l = 1; l < 6; ++l) {
          float s2 = 2.f*s*c, c2 = c*c - s*s;
          S[d][l]=s2; C[d][l]=c2; s=s2; c=c2;
        }
      }
      half8 e0, e1 = z;
      if (g == 0) {
        e0 = mkh8(S[0][0],S[0][1],S[0][2],S[0][3],S[0][4],S[0][5],C[0][0],C[0][1]);
        e1 = mkh8(C[2][2],C[2][3],C[2][4],C[2][5],0.f,0.f,0.f,0.f);
      } else if (g == 1) {
        e0 = mkh8(C[0][2],C[0][3],C[0][4],C[0][5],S[1][0],S[1][1],S[1][2],S[1][3]);
      } else if (g == 2) {
        e0 = mkh8(S[1][4],S[1][5],C[1][0],C[1][1],C[1][2],C[1][3],C[1][4],C[1][5]);
      } else {
        e0 = mkh8(S[2][0],S[2][1],S[2][2],S[2][3],S[2][4],S[2][5],C[2][0],C[2][1]);
      }
      bf[st][0]=e0; bf[st][1]=e1;
      float dv = (g < 3) ? dirs[(size_t)p*3 + g] : 0.f;
      float xx = dv*PI;
      float s1 = __sinf(xx), c1 = __cosf(xx);
      float sa[4], ca[4]; sa[0]=s1; ca[0]=c1;
#pragma unroll
      for (int l = 1; l < 4; ++l) {
        float s2 = 2.f*s1*c1, c2 = c1*c1 - s1*s1;
        sa[l]=s2; ca[l]=c2; s1=s2; c1=c2;
      }
      dirf[st] = (g < 3) ? mkh8(sa[0],sa[1],sa[2],sa[3],ca[0],ca[1],ca[2],ca[3]) : z;
    }

    // ---- MLP trunk, all weights LDS-resident, no barriers ----
    chunk64< 80,2,0,true ,0>(&W[G1A], lane, b1,     bf, pk);
    chunk64< 80,2,4,true ,0>(&W[G1B], lane, b1+64,  bf, pk);
    REB4();
    chunk64<256,4,0,true ,7>(&W[G2A], lane, b2,     bf, pk);
    chunk64<256,4,4,true ,7>(&W[G2B], lane, b2+64,  bf, pk);
    REB4();
    chunk64<256,4,0,true ,7>(&W[G3A], lane, b3,     bf, pk);
    chunk64<256,4,4,true ,7>(&W[G3B], lane, b3+64,  bf, pk);
    REB4();
    chunk64<256,4,0,true ,7>(&W[G4A], lane, b4,     bf, pk);
    chunk64<256,4,4,true ,7>(&W[G4B], lane, b4+64,  bf, pk);
    REB4();   // bf = geo_feat fragments

    // ---- density head: dot with d_w stash (c1 pad cols), wave-local ----
    {
      half8 dv[4];
#pragma unroll
      for (int ks = 0; ks < 4; ++ks) {
        int o = ks*4 + g;
        dv[ks] = *(const half8*)((const char*)&W[C1C] + o*320 + (304 ^ ((o & 3) << 4)));
      }
      float dsum[4];
#pragma unroll
      for (int st = 0; st < 4; ++st) {
        float a = 0.f;
#pragma unroll
        for (int ks = 0; ks < 4; ++ks)
#pragma unroll
          for (int q = 0; q < 4; ++q) {
#if __has_builtin(__builtin_amdgcn_fdot2)
            half2v xv = {bf[st][ks][2*q], bf[st][ks][2*q+1]};
            half2v wv = {dv[ks][2*q],     dv[ks][2*q+1]};
            a = __builtin_amdgcn_fdot2(xv, wv, a, false);
#else
            a += (float)bf[st][ks][2*q]   * (float)dv[ks][2*q];
            a += (float)bf[st][ks][2*q+1] * (float)dv[ks][2*q+1];
#endif
          }
        a += __shfl_xor(a, 16);
        a += __shfl_xor(a, 32);
        dsum[st] = a;
      }
      if (g == 0) {
        float d0 = bd[0];
#pragma unroll
        for (int st = 0; st < 4; ++st) {
          float x = dsum[st] + d0;
          out[(size_t)3*N + pbase + st*16 + n] = fmaxf(x,0.f) + log1pf(__expf(-fabsf(x)));
        }
      }
    }

    chunk64<256,4,0,false,7>(&W[FAC], lane, bfl,    bf, pk);
    chunk64<256,4,4,false,7>(&W[FBC], lane, bfl+64, bf, pk);
    REB4();   // bf = feature fragments
#pragma unroll
    for (int st = 0; st < 4; ++st) bf[st][4] = dirf[st];

    chunk64<320,5,0,true ,3>(&W[C1C], lane, bc1,    bf, pk);
    // c2 input (64 dims -> 2 k-steps)
#pragma unroll
    for (int st = 0; st < 4; ++st) {
      bf[st][0] = mk8(pk[0][st], pk[1][st]);
      bf[st][1] = mk8(pk[2][st], pk[3][st]);
    }

    // ---- rgb head ----
    {
      const char* lb = (const char*)&W[C2C] + n*128;
      const int swz = (n & 7) << 4;
      half8 wf[2];
#pragma unroll
      for (int ks = 0; ks < 2; ++ks)
        wf[ks] = *(const half8*)(lb + ((ks*64 + g*16) ^ swz));
      f32x4 a[4];
#pragma unroll
      for (int st = 0; st < 4; ++st) a[st] = f32x4{0.f,0.f,0.f,0.f};
      __builtin_amdgcn_s_setprio(1);
#pragma unroll
      for (int ks = 0; ks < 2; ++ks)
#pragma unroll
        for (int st = 0; st < 4; ++st) a[st] = MFMA16(wf[ks], bf[st][ks], a[st]);
      __builtin_amdgcn_s_setprio(0);
      if (g == 0) {
        float c0 = bc2[0], c1v = bc2[1], c2v = bc2[2];
#pragma unroll
        for (int st = 0; st < 4; ++st) {
          size_t p = (size_t)(pbase + st*16 + n);
          out[p*3+0] = 1.f/(1.f + __expf(-(a[st][0] + c0)));
          out[p*3+1] = 1.f/(1.f + __expf(-(a[st][1] + c1v)));
          out[p*3+2] = 1.f/(1.f + __expf(-(a[st][2] + c2v)));
        }
      }
    }
  }
}

extern "C" void kernel_launch(void* const* d_in, const int* in_sizes, int n_in,
                              void* d_out, int out_size, void* d_ws, size_t ws_size,
                              hipStream_t stream) {
  const float* pos = (const float*)d_in[0];
  const float* dirs = (const float*)d_in[1];
  const float* g1w = (const float*)d_in[2];
  const float* g1b = (const float*)d_in[3];
  const float* g2w = (const float*)d_in[4];
  const float* g2b = (const float*)d_in[5];
  const float* g3w = (const float*)d_in[6];
  const float* g3b = (const float*)d_in[7];
  const float* g4w = (const float*)d_in[8];
  const float* g4b = (const float*)d_in[9];
  const float* dw  = (const float*)d_in[10];
  const float* db  = (const float*)d_in[11];
  const float* fw  = (const float*)d_in[12];
  const float* fb  = (const float*)d_in[13];
  const float* c1w = (const float*)d_in[14];
  const float* c1b = (const float*)d_in[15];
  const float* c2w = (const float*)d_in[16];
  const float* c2b = (const float*)d_in[17];

  int N = in_sizes[0] / 3;   // 1048576
  _Float16* img = (_Float16*)d_ws;

  prep<<<(IMG_HALVES + 255)/256, 256, 0, stream>>>(
      g1w, g2w, g3w, g4w, dw, fw, c1w, c2w, img);

  // 1 block/CU (160KB LDS), 16 waves each, 4 chunks of 64 pts per wave
  nerf_fused<<<N/4096, 1024, 0, stream>>>(
      pos, dirs, img, g1b, g2b, g3b, g4b, db, fb, c1b, c2b,
      (float*)d_out, N);
}

// Round 4
// 266.688 us; speedup vs baseline: 2.4790x; 2.4790x over previous
//
#include <hip/hip_runtime.h>

// TinyNeRF fused MLP, fp16 MFMA 16x16x32, fp32 accum.
// Round-4: round-3 architecture (ALL weights persistent in LDS, 160 KB,
// zero steady-state barriers, in-register layer chaining via K-permuted
// weights) with the block shape fixed: 512 threads (8 waves = 2/SIMD),
// __launch_bounds__(512,2) -> 256-VGPR budget, no spill (round 3's 1024-thr
// block capped VGPR at 64 and spilled ~1GB to scratch).
// Each wave processes 8 batches of 64 points; grid = 256 (1 block/CU).

typedef _Float16 half8 __attribute__((ext_vector_type(8)));
typedef _Float16 half2v __attribute__((ext_vector_type(2)));
typedef float f32x4 __attribute__((ext_vector_type(4)));

typedef __attribute__((address_space(1))) const unsigned int GU32;
typedef __attribute__((address_space(3))) unsigned int LU32;

#define MFMA16(A,B,C) __builtin_amdgcn_mfma_f32_16x16x32_f16(A,B,C,0,0,0)

#define G1A 0
#define G1B 2560
#define G2A 5120
#define G2B 13312
#define G3A 21504
#define G3B 29696
#define G4A 37888
#define G4B 46080
#define FAC 54272
#define FBC 62464
#define C1C 70656
#define C2C 80896
#define IMG_HALVES 81920

// K-axis permutation: B-slot (ks,g,jj) holds output dim
// (2ks + jj>>2)*16 + g*4 + (jj&3) of the previous layer.
__device__ __forceinline__ int permk(int s){
  int ks = s >> 5, gg = (s >> 3) & 3, jj = s & 7;
  return (2*ks + (jj >> 2))*16 + gg*4 + (jj & 3);
}

__global__ void prep(const float* __restrict__ g1w, const float* __restrict__ g2w,
                     const float* __restrict__ g3w, const float* __restrict__ g4w,
                     const float* __restrict__ dw,  const float* __restrict__ fw,
                     const float* __restrict__ c1w, const float* __restrict__ c2w,
                     _Float16* __restrict__ img) {
  int i = blockIdx.x*256 + threadIdx.x;
  if (i >= IMG_HALVES) return;
  float v = 0.f;
  size_t byteoff;
  if (i < G2A) {                       // g1: linear [2][64][40]
    int hf = (i < G1B) ? 0 : 1;
    int r = i - hf*G1B;
    int o = r / 40, s = r % 40;
    v = (s < 36) ? g1w[s*128 + hf*64 + o] : 0.f;
    byteoff = (size_t)i*2;
  } else if (i < C1C) {                // six [64][128] chunks, swz7, permk
    int ci = (i - G2A) >> 13;
    int r  = (i - G2A) & 8191;
    int o = r >> 7, s = r & 127;
    const float* W = (ci < 2) ? g2w : (ci < 4) ? g3w : (ci < 6) ? g4w : fw;
    int obase = (ci & 1)*64;
    v = W[permk(s)*128 + obase + o];
    byteoff = (size_t)(G2A + ci*8192)*2 + o*256 + ((2*s) ^ ((o & 7) << 4));
  } else if (i < C2C) {                // c1 [64][160], swz2
    int r = i - C1C;
    int o = r / 160, s = r % 160;
    if (s < 128)      v = c1w[permk(s)*64 + o];
    else if (s < 152) v = c1w[s*64 + o];
    else if (o < 16)  v = dw[permk(8*o + (s - 152))];   // d_w stash
    else              v = 0.f;
    byteoff = (size_t)C1C*2 + o*320 + ((2*s) ^ ((o & 3) << 4));
  } else {                             // c2 [16][64], swz7
    int r = i - C2C;
    int o = r >> 6, s = r & 63;
    v = (o < 3) ? c2w[permk(s)*3 + o] : 0.f;
    byteoff = (size_t)C2C*2 + o*128 + ((2*s) ^ ((o & 7) << 4));
  }
  *(_Float16*)((char*)img + byteoff) = (_Float16)v;
}

__device__ __forceinline__ half8 mk8(uint2 a, uint2 b){
  union { unsigned int u[4]; half8 h; } x;
  x.u[0]=a.x; x.u[1]=a.y; x.u[2]=b.x; x.u[3]=b.y; return x.h;
}
__device__ __forceinline__ half8 mkh8(float a,float b,float c,float d,
                                      float e,float f,float g,float h){
  half8 r; r[0]=(_Float16)a; r[1]=(_Float16)b; r[2]=(_Float16)c; r[3]=(_Float16)d;
  r[4]=(_Float16)e; r[5]=(_Float16)f; r[6]=(_Float16)g; r[7]=(_Float16)h; return r;
}
__device__ __forceinline__ uint2 pack4(float a0,float a1,float a2,float a3,bool relu){
  if (relu){ a0=fmaxf(a0,0.f); a1=fmaxf(a1,0.f); a2=fmaxf(a2,0.f); a3=fmaxf(a3,0.f); }
  union { _Float16 h[4]; uint2 u; } x;
  x.h[0]=(_Float16)a0; x.h[1]=(_Float16)a1; x.h[2]=(_Float16)a2; x.h[3]=(_Float16)a3;
  return x.u;
}

// one og-half: O=64 (og 0..3) from persistent-LDS chunk at `buf`
template<int KROWB, int KS, int PKB, bool RELU, int SWZM>
__device__ __forceinline__ void chunk64(const _Float16* buf, int lane,
                                        const float* __restrict__ bias,
                                        const half8 (&bf)[4][5], uint2 (&pk)[8][4]) {
  const int g = lane >> 4, n = lane & 15;
  const int swz = (n & SWZM) << 4;
  const char* lb = (const char*)buf + n*KROWB;
#pragma unroll
  for (int og = 0; og < 4; ++og) {
    half8 wf[KS];
#pragma unroll
    for (int ks = 0; ks < KS; ++ks)
      wf[ks] = *(const half8*)(lb + og*16*KROWB + ((ks*64 + g*16) ^ swz));
    f32x4 bv = *(const f32x4*)(bias + og*16 + g*4);
    f32x4 acc[4];
#pragma unroll
    for (int st = 0; st < 4; ++st) acc[st] = bv;
    __builtin_amdgcn_s_setprio(1);
#pragma unroll
    for (int ks = 0; ks < KS; ++ks)
#pragma unroll
      for (int st = 0; st < 4; ++st)
        acc[st] = MFMA16(wf[ks], bf[st][ks], acc[st]);
    __builtin_amdgcn_s_setprio(0);
#pragma unroll
    for (int st = 0; st < 4; ++st)
      pk[PKB+og][st] = pack4(acc[st][0], acc[st][1], acc[st][2], acc[st][3], RELU);
  }
}

#define REB4() do{ \
  _Pragma("unroll") \
  for (int st_ = 0; st_ < 4; ++st_){ \
    half8 n0 = mk8(pk[0][st_], pk[1][st_]); \
    half8 n1 = mk8(pk[2][st_], pk[3][st_]); \
    half8 n2 = mk8(pk[4][st_], pk[5][st_]); \
    half8 n3 = mk8(pk[6][st_], pk[7][st_]); \
    bf[st_][0]=n0; bf[st_][1]=n1; bf[st_][2]=n2; bf[st_][3]=n3; \
  } \
}while(0)

__global__ __launch_bounds__(512, 2) void nerf_fused(
    const float* __restrict__ pos, const float* __restrict__ dirs,
    const _Float16* __restrict__ img,
    const float* __restrict__ b1, const float* __restrict__ b2,
    const float* __restrict__ b3, const float* __restrict__ b4,
    const float* __restrict__ bd, const float* __restrict__ bfl,
    const float* __restrict__ bc1, const float* __restrict__ bc2,
    float* __restrict__ out, int N) {
  __shared__ __align__(16) _Float16 W[IMG_HALVES];   // 160 KB exactly
  const int tid = threadIdx.x, wave = tid >> 6, lane = tid & 63;
  const int g = lane >> 4, n = lane & 15;

  // one-time weight stage: 512 thr x 20 x 16B = 163840 B
#pragma unroll
  for (int r = 0; r < 20; ++r)
    __builtin_amdgcn_global_load_lds((GU32*)((const char*)img + tid*16 + (size_t)r*8192),
                                     (LU32*)((char*)&W[0] + tid*16 + r*8192), 16, 0, 0);
  __syncthreads();   // the only barrier

  half8 bf[4][5];
  uint2 pk[8][4];
  half8 dirf[4];
  const float PI = 3.14159265358979f;
  half8 z = {};

  for (int it = 0; it < 8; ++it) {
    const int pbase = blockIdx.x*4096 + wave*512 + it*64;

    // ---- encode directly into B-fragment form ----
#pragma unroll
    for (int st = 0; st < 4; ++st) {
      int p = pbase + st*16 + n;
      float S[3][6], C[3][6];
      const float* pp = pos + (size_t)p*3;
#pragma unroll
      for (int d = 0; d < 3; ++d) {
        float x = pp[d]*PI;
        float s = __sinf(x), c = __cosf(x);
        S[d][0]=s; C[d][0]=c;
#pragma unroll
        for (int l = 1; l < 6; ++l) {
          float s2 = 2.f*s*c, c2 = c*c - s*s;
          S[d][l]=s2; C[d][l]=c2; s=s2; c=c2;
        }
      }
      half8 e0, e1 = z;
      if (g == 0) {
        e0 = mkh8(S[0][0],S[0][1],S[0][2],S[0][3],S[0][4],S[0][5],C[0][0],C[0][1]);
        e1 = mkh8(C[2][2],C[2][3],C[2][4],C[2][5],0.f,0.f,0.f,0.f);
      } else if (g == 1) {
        e0 = mkh8(C[0][2],C[0][3],C[0][4],C[0][5],S[1][0],S[1][1],S[1][2],S[1][3]);
      } else if (g == 2) {
        e0 = mkh8(S[1][4],S[1][5],C[1][0],C[1][1],C[1][2],C[1][3],C[1][4],C[1][5]);
      } else {
        e0 = mkh8(S[2][0],S[2][1],S[2][2],S[2][3],S[2][4],S[2][5],C[2][0],C[2][1]);
      }
      bf[st][0]=e0; bf[st][1]=e1;
      float dv = (g < 3) ? dirs[(size_t)p*3 + g] : 0.f;
      float xx = dv*PI;
      float s1 = __sinf(xx), c1 = __cosf(xx);
      float sa[4], ca[4]; sa[0]=s1; ca[0]=c1;
#pragma unroll
      for (int l = 1; l < 4; ++l) {
        float s2 = 2.f*s1*c1, c2 = c1*c1 - s1*s1;
        sa[l]=s2; ca[l]=c2; s1=s2; c1=c2;
      }
      dirf[st] = (g < 3) ? mkh8(sa[0],sa[1],sa[2],sa[3],ca[0],ca[1],ca[2],ca[3]) : z;
    }

    // ---- MLP trunk, all weights LDS-resident, no barriers ----
    chunk64< 80,2,0,true ,0>(&W[G1A], lane, b1,     bf, pk);
    chunk64< 80,2,4,true ,0>(&W[G1B], lane, b1+64,  bf, pk);
    REB4();
    chunk64<256,4,0,true ,7>(&W[G2A], lane, b2,     bf, pk);
    chunk64<256,4,4,true ,7>(&W[G2B], lane, b2+64,  bf, pk);
    REB4();
    chunk64<256,4,0,true ,7>(&W[G3A], lane, b3,     bf, pk);
    chunk64<256,4,4,true ,7>(&W[G3B], lane, b3+64,  bf, pk);
    REB4();
    chunk64<256,4,0,true ,7>(&W[G4A], lane, b4,     bf, pk);
    chunk64<256,4,4,true ,7>(&W[G4B], lane, b4+64,  bf, pk);
    REB4();   // bf = geo_feat fragments

    // ---- density head: dot with d_w stash (c1 pad cols), wave-local ----
    {
      half8 dv[4];
#pragma unroll
      for (int ks = 0; ks < 4; ++ks) {
        int o = ks*4 + g;
        dv[ks] = *(const half8*)((const char*)&W[C1C] + o*320 + (304 ^ ((o & 3) << 4)));
      }
      float dsum[4];
#pragma unroll
      for (int st = 0; st < 4; ++st) {
        float a = 0.f;
#pragma unroll
        for (int ks = 0; ks < 4; ++ks)
#pragma unroll
          for (int q = 0; q < 4; ++q) {
#if __has_builtin(__builtin_amdgcn_fdot2)
            half2v xv = {bf[st][ks][2*q], bf[st][ks][2*q+1]};
            half2v wv = {dv[ks][2*q],     dv[ks][2*q+1]};
            a = __builtin_amdgcn_fdot2(xv, wv, a, false);
#else
            a += (float)bf[st][ks][2*q]   * (float)dv[ks][2*q];
            a += (float)bf[st][ks][2*q+1] * (float)dv[ks][2*q+1];
#endif
          }
        a += __shfl_xor(a, 16);
        a += __shfl_xor(a, 32);
        dsum[st] = a;
      }
      if (g == 0) {
        float d0 = bd[0];
#pragma unroll
        for (int st = 0; st < 4; ++st) {
          float x = dsum[st] + d0;
          out[(size_t)3*N + pbase + st*16 + n] = fmaxf(x,0.f) + log1pf(__expf(-fabsf(x)));
        }
      }
    }

    chunk64<256,4,0,false,7>(&W[FAC], lane, bfl,    bf, pk);
    chunk64<256,4,4,false,7>(&W[FBC], lane, bfl+64, bf, pk);
    REB4();   // bf = feature fragments
#pragma unroll
    for (int st = 0; st < 4; ++st) bf[st][4] = dirf[st];

    chunk64<320,5,0,true ,3>(&W[C1C], lane, bc1,    bf, pk);
    // c2 input (64 dims -> 2 k-steps)
#pragma unroll
    for (int st = 0; st < 4; ++st) {
      bf[st][0] = mk8(pk[0][st], pk[1][st]);
      bf[st][1] = mk8(pk[2][st], pk[3][st]);
    }

    // ---- rgb head ----
    {
      const char* lb = (const char*)&W[C2C] + n*128;
      const int swz = (n & 7) << 4;
      half8 wf[2];
#pragma unroll
      for (int ks = 0; ks < 2; ++ks)
        wf[ks] = *(const half8*)(lb + ((ks*64 + g*16) ^ swz));
      f32x4 a[4];
#pragma unroll
      for (int st = 0; st < 4; ++st) a[st] = f32x4{0.f,0.f,0.f,0.f};
      __builtin_amdgcn_s_setprio(1);
#pragma unroll
      for (int ks = 0; ks < 2; ++ks)
#pragma unroll
        for (int st = 0; st < 4; ++st) a[st] = MFMA16(wf[ks], bf[st][ks], a[st]);
      __builtin_amdgcn_s_setprio(0);
      if (g == 0) {
        float c0 = bc2[0], c1v = bc2[1], c2v = bc2[2];
#pragma unroll
        for (int st = 0; st < 4; ++st) {
          size_t p = (size_t)(pbase + st*16 + n);
          out[p*3+0] = 1.f/(1.f + __expf(-(a[st][0] + c0)));
          out[p*3+1] = 1.f/(1.f + __expf(-(a[st][1] + c1v)));
          out[p*3+2] = 1.f/(1.f + __expf(-(a[st][2] + c2v)));
        }
      }
    }
  }
}

extern "C" void kernel_launch(void* const* d_in, const int* in_sizes, int n_in,
                              void* d_out, int out_size, void* d_ws, size_t ws_size,
                              hipStream_t stream) {
  const float* pos = (const float*)d_in[0];
  const float* dirs = (const float*)d_in[1];
  const float* g1w = (const float*)d_in[2];
  const float* g1b = (const float*)d_in[3];
  const float* g2w = (const float*)d_in[4];
  const float* g2b = (const float*)d_in[5];
  const float* g3w = (const float*)d_in[6];
  const float* g3b = (const float*)d_in[7];
  const float* g4w = (const float*)d_in[8];
  const float* g4b = (const float*)d_in[9];
  const float* dw  = (const float*)d_in[10];
  const float* db  = (const float*)d_in[11];
  const float* fw  = (const float*)d_in[12];
  const float* fb  = (const float*)d_in[13];
  const float* c1w = (const float*)d_in[14];
  const float* c1b = (const float*)d_in[15];
  const float* c2w = (const float*)d_in[16];
  const float* c2b = (const float*)d_in[17];

  int N = in_sizes[0] / 3;   // 1048576
  _Float16* img = (_Float16*)d_ws;

  prep<<<(IMG_HALVES + 255)/256, 256, 0, stream>>>(
      g1w, g2w, g3w, g4w, dw, fw, c1w, c2w, img);

  // 1 block/CU (160KB LDS), 8 waves (2/SIMD), 8 batches of 64 pts per wave
  nerf_fused<<<N/4096, 512, 0, stream>>>(
      pos, dirs, img, g1b, g2b, g3b, g4b, db, fb, c1b, c2b,
      (float*)d_out, N);
}